// Round 6
// baseline (567.171 us; speedup 1.0000x reference)
//
#include <hip/hip_runtime.h>
#include <hip/hip_bf16.h>

typedef __attribute__((ext_vector_type(4))) float f32x4;
typedef __attribute__((ext_vector_type(8))) short short8;

#define HH 512
#define BB 32
#define SS 2048
#define KK 1024  // 2H

__device__ __forceinline__ unsigned short f2bf(float f) {
    unsigned int u = __float_as_uint(f);
    u += 0x7fffu + ((u >> 16) & 1u);
    return (unsigned short)(u >> 16);
}

__device__ __forceinline__ ushort4 pack4(float4 f) {
    ushort4 p;
    p.x = f2bf(f.x); p.y = f2bf(f.y); p.z = f2bf(f.z); p.w = f2bf(f.w);
    return p;
}

__device__ __forceinline__ float fast_tanh(float x) {
    float e = __expf(2.0f * x);
    return 1.0f - 2.0f / (e + 1.0f);
}

// fp32x8 -> bf16x8 (RNE); scalar casts lower to v_cvt_pk_bf16_f32.
__device__ __forceinline__ short8 cvt_bf8(const float4& a0, const float4& a1) {
    short8 o;
    union { __hip_bfloat16 h; unsigned short u; } c;
    c.h = __float2bfloat16(a0.x); o[0] = (short)c.u;
    c.h = __float2bfloat16(a0.y); o[1] = (short)c.u;
    c.h = __float2bfloat16(a0.z); o[2] = (short)c.u;
    c.h = __float2bfloat16(a0.w); o[3] = (short)c.u;
    c.h = __float2bfloat16(a1.x); o[4] = (short)c.u;
    c.h = __float2bfloat16(a1.y); o[5] = (short)c.u;
    c.h = __float2bfloat16(a1.z); o[6] = (short)c.u;
    c.h = __float2bfloat16(a1.w); o[7] = (short)c.u;
    return o;
}

// ---------------- kernel 1: spb[b][h] = output[b]·W_s[h] + b_attn[h] ----------------
__global__ __launch_bounds__(256)
void spb_kernel(const float* __restrict__ out_state,
                const float* __restrict__ W,
                const float* __restrict__ bias,
                float* __restrict__ spb) {
    int wave = threadIdx.x >> 6, lane = threadIdx.x & 63;
    int g = blockIdx.x * 4 + wave;       // 16384 (b,h) pairs
    int b = g >> 9, h = g & 511;
    const float* wr = W + (size_t)h * 1536;      // W_s row h
    const float* ov = out_state + b * HH;
    float4 w0 = *(const float4*)(wr + lane * 8);
    float4 w1 = *(const float4*)(wr + lane * 8 + 4);
    float4 o0 = *(const float4*)(ov + lane * 8);
    float4 o1 = *(const float4*)(ov + lane * 8 + 4);
    float d = w0.x * o0.x + w0.y * o0.y + w0.z * o0.z + w0.w * o0.w
            + w1.x * o1.x + w1.y * o1.y + w1.z * o1.z + w1.w * o1.w;
    d += __shfl_xor(d, 1); d += __shfl_xor(d, 2); d += __shfl_xor(d, 4);
    d += __shfl_xor(d, 8); d += __shfl_xor(d, 16); d += __shfl_xor(d, 32);
    if (lane == 0) spb[g] = d + bias[h];
}

// ------- kernel 2: W_e -> bf16, FRAG-MAJOR layout Wt[kt][g][lane][8] -------
// g = h>>4, lane = (q<<4)|(h&15), q = (k>>3)&3: a wave's B-frag read is
// 64 lanes x 16B contiguous (1 KB per (kt,g) frag).
__global__ void wconv_kernel(const float* __restrict__ W, unsigned short* __restrict__ Wt) {
    int idx = blockIdx.x * 256 + threadIdx.x;   // 65536 threads, 8 elems each
    int e8 = idx * 8;
    int h = e8 >> 10;        // [0,512)
    int k = e8 & 1023;       // multiple of 8
    const float* src = W + (size_t)h * 1536 + 512 + k;
    float4 w0 = *(const float4*)src;
    float4 w1 = *(const float4*)(src + 4);
    int kt = k >> 5;
    int q  = (k >> 3) & 3;
    int g  = h >> 4;
    int r  = h & 15;
    int ln = (q << 4) | r;
    unsigned short* dst = Wt + (size_t)kt * 16384 + g * 512 + ln * 8;
    *(ushort4*)dst = pack4(w0);
    *(ushort4*)(dst + 4) = pack4(w1);
}

// ---------------- kernel 3: fused GEMM + tanh + v-dot -> scores[b][s] ----------------
// v6: BARRIER-FREE register streaming. A has zero K-reuse -> no LDS staging at
// all; each wave loads its own A-frags global->reg (fp32, one-kt prefetch into
// fA, cvt at use). B-frags ring in registers from L2-resident frag-major Wt,
// reloaded immediately after last use (distance ~1 kt ~620cy >> L2 latency).
// No __syncthreads in the K-loop: waves self-pace, the compiler emits counted
// vmcnt waits (cvt waits its A batch, leaving bf in flight). A re-reads by the
// 8 col-waves of a block hit L1 (16 KB/kt frame). Per-wave tile and fragment
// conventions identical to v5 (8mt x 4nf, epilogue unchanged).
__global__ __launch_bounds__(512, 2)
void attn_gemm(const float* __restrict__ enc, const unsigned short* __restrict__ Wt,
               const float* __restrict__ spb, const float* __restrict__ vvec,
               float* __restrict__ scores) {
    __shared__ float red[8][128];   // epilogue only (4 KB)

    const int tid = threadIdx.x;
    const int w = tid >> 6;
    const int lane = tid & 63;
    const int r = lane & 15;
    const int q = lane >> 4;
    const int b = blockIdx.x >> 4;          // 32 b x 16 s-tiles
    const int s0 = (blockIdx.x & 15) << 7;  // 128 rows per tile
    const int bS = b * SS + s0;

    // A-frag sources: row = s0 + mt*16 + r, k = kt*32 + q*8 (+0..7)
    const float* aP[8];
    #pragma unroll
    for (int mt = 0; mt < 8; ++mt)
        aP[mt] = enc + (size_t)(bS + mt * 16 + r) * KK + q * 8;

    // B frags: frag-major Wt, wave w covers col groups g = w*4+nf
    const short8* wp = (const short8*)Wt + (size_t)(w * 4) * 64 + lane;
    // + nf*64 per frag, + kt*2048 per K-tile (short8 units)

    f32x4 acc[8][4] = {};
    float4 fA[8][2];
    short8 bfr[4];

    // ---- prologue: A(kt=0) + bf(kt=0) ----
    #pragma unroll
    for (int mt = 0; mt < 8; ++mt) {
        fA[mt][0] = *(const float4*)(aP[mt]);
        fA[mt][1] = *(const float4*)(aP[mt] + 4);
    }
    #pragma unroll
    for (int nf = 0; nf < 4; ++nf) bfr[nf] = wp[nf * 64];

    // ---- K loop: 32 kt, no barriers ----
    #pragma unroll 1
    for (int kt = 0; kt < 32; ++kt) {
        const int kadv = (kt + 1) * 32;     // float offset of next kt
        short8 af[4];

        // half 0: mt 0..3 — cvt (waits A[0..3] via counted vmcnt), refill, MFMA
        #pragma unroll
        for (int mt = 0; mt < 4; ++mt)
            af[mt] = cvt_bf8(fA[mt][0], fA[mt][1]);
        if (kt < 31) {
            #pragma unroll
            for (int mt = 0; mt < 4; ++mt) {
                fA[mt][0] = *(const float4*)(aP[mt] + kadv);
                fA[mt][1] = *(const float4*)(aP[mt] + kadv + 4);
            }
        }
        #pragma unroll
        for (int nf = 0; nf < 4; ++nf)
            #pragma unroll
            for (int mt = 0; mt < 4; ++mt)
                acc[mt][nf] = __builtin_amdgcn_mfma_f32_16x16x32_bf16(
                    af[mt], bfr[nf], acc[mt][nf], 0, 0, 0);

        // half 1: mt 4..7 — cvt, refill, MFMA + bf ring reload after last use
        #pragma unroll
        for (int mt = 0; mt < 4; ++mt)
            af[mt] = cvt_bf8(fA[mt + 4][0], fA[mt + 4][1]);
        if (kt < 31) {
            #pragma unroll
            for (int mt = 0; mt < 4; ++mt) {
                fA[mt + 4][0] = *(const float4*)(aP[mt + 4] + kadv);
                fA[mt + 4][1] = *(const float4*)(aP[mt + 4] + kadv + 4);
            }
        }
        #pragma unroll
        for (int nf = 0; nf < 4; ++nf) {
            #pragma unroll
            for (int mt = 0; mt < 4; ++mt)
                acc[mt + 4][nf] = __builtin_amdgcn_mfma_f32_16x16x32_bf16(
                    af[mt], bfr[nf], acc[mt + 4][nf], 0, 0, 0);
            if (kt < 31)
                bfr[nf] = wp[(size_t)(kt + 1) * 2048 + nf * 64];
        }
    }

    // ---- epilogue: partial score = sum over this wave's 64 cols of v[h]*tanh(.+spb)
    float vh[4], sh[4];
    #pragma unroll
    for (int nf = 0; nf < 4; ++nf) {
        int h = w * 64 + nf * 16 + r;
        vh[nf] = vvec[h];
        sh[nf] = spb[b * HH + h];
    }
    float rowacc[8][4] = {};
    #pragma unroll
    for (int mt = 0; mt < 8; ++mt)
        #pragma unroll
        for (int nf = 0; nf < 4; ++nf)
            #pragma unroll
            for (int i = 0; i < 4; ++i) {
                float x = acc[mt][nf][i] + sh[nf];
                rowacc[mt][i] += vh[nf] * fast_tanh(x);
            }
    #pragma unroll
    for (int mt = 0; mt < 8; ++mt)
        #pragma unroll
        for (int i = 0; i < 4; ++i) {
            float t = rowacc[mt][i];
            t += __shfl_xor(t, 1);
            t += __shfl_xor(t, 2);
            t += __shfl_xor(t, 4);
            t += __shfl_xor(t, 8);
            rowacc[mt][i] = t;
        }
    if (r == 0) {
        #pragma unroll
        for (int mt = 0; mt < 8; ++mt)
            #pragma unroll
            for (int i = 0; i < 4; ++i)
                red[w][mt * 16 + q * 4 + i] = rowacc[mt][i];  // row = mt*16+q*4+i
    }
    __syncthreads();
    if (tid < 128) {
        float sum = 0.f;
        #pragma unroll
        for (int ww = 0; ww < 8; ++ww) sum += red[ww][tid];
        scores[bS + tid] = sum;
    }
}

// ---------------- kernel 4: masked softmax over S per batch ----------------
__global__ void softmax_kernel(const float* __restrict__ scores,
                               const int* __restrict__ mask,
                               float* __restrict__ out) {
    __shared__ float red[256];
    int b = blockIdx.x, tid = threadIdx.x;
    float x[8];
    #pragma unroll
    for (int i = 0; i < 8; ++i) {
        int s = tid + i * 256;
        float sc = scores[b * SS + s];
        if (mask[b * SS + s] == 0) sc -= 1000.0f;
        x[i] = sc;
    }
    float mx = x[0];
    #pragma unroll
    for (int i = 1; i < 8; ++i) mx = fmaxf(mx, x[i]);
    red[tid] = mx;
    __syncthreads();
    for (int o = 128; o > 0; o >>= 1) {
        if (tid < o) red[tid] = fmaxf(red[tid], red[tid + o]);
        __syncthreads();
    }
    mx = red[0];
    __syncthreads();
    float e[8], sum = 0.f;
    #pragma unroll
    for (int i = 0; i < 8; ++i) { e[i] = __expf(x[i] - mx); sum += e[i]; }
    red[tid] = sum;
    __syncthreads();
    for (int o = 128; o > 0; o >>= 1) {
        if (tid < o) red[tid] += red[tid + o];
        __syncthreads();
    }
    float inv = 1.0f / red[0];
    #pragma unroll
    for (int i = 0; i < 8; ++i) out[b * SS + tid + i * 256] = e[i] * inv;
}

extern "C" void kernel_launch(void* const* d_in, const int* in_sizes, int n_in,
                              void* d_out, int out_size, void* d_ws, size_t ws_size,
                              hipStream_t stream) {
    const float* out_state = (const float*)d_in[0];   // (32, 512)
    const float* enc       = (const float*)d_in[1];   // (32, 2048, 1024)
    const int*   mask      = (const int*)d_in[2];     // (32, 2048)
    const float* W_attn    = (const float*)d_in[3];   // (512, 1536)
    const float* b_attn    = (const float*)d_in[4];   // (512,)
    const float* vvec      = (const float*)d_in[5];   // (512,)
    float* out = (float*)d_out;                       // (32, 1, 2048)

    char* ws = (char*)d_ws;
    float*          spb    = (float*)ws;                         // 64 KB
    unsigned short* Wt     = (unsigned short*)(ws + 65536);      // 1 MB
    float*          scores = (float*)(ws + 65536 + 1048576);     // 256 KB

    spb_kernel<<<4096, 256, 0, stream>>>(out_state, W_attn, b_attn, spb);
    wconv_kernel<<<256, 256, 0, stream>>>(W_attn, Wt);
    attn_gemm<<<512, 512, 0, stream>>>(enc, Wt, spb, vvec, scores);
    softmax_kernel<<<32, 256, 0, stream>>>(scores, mask, out);
}